// Round 3
// baseline (2061.419 us; speedup 1.0000x reference)
//
#include <hip/hip_runtime.h>

// ---------------------------------------------------------------------------
// WindowAttention on MI355X (gfx950) — v3.1: register-resident QKV weights.
// B_=4096 windows, S=49 (7x7), D=384, H=6 heads, hd=64, Wn=64 masks.
//
// v3 design (v2 was drain-barrier-bound: 72 vmcnt(0) syncthreads/block):
//   - QKV GEMM n-split per wave; B-fragments loaded straight from L2 into
//     VGPRs (wfrag[3][12], 144 regs) once per head; W(h+1) prefetched into
//     the dead regs under epilogue+attention. NO weight staging, NO barriers,
//     NO LDS B-reads in the k-loop.
//   - x converted to bf16 once per block into LDS (XOR-swizzled, 37.6 KB).
//   - 2 barriers/head, lgkmcnt-only (global loads stay in flight across).
//   - all LDS stride-64 + row-XOR swizzle (elem ^= (row&7)<<3) -> conflict-
//     free b128 access; LDS 70,400 B -> 2 blocks/CU, __launch_bounds__(256,2).
// v3.1 robustness deltas (round-2 container failure attribution):
//   - barrier = asm waitcnt(lgkm) + __builtin_amdgcn_s_barrier() bracketed by
//     compiler fences (m201-verified pattern) instead of raw asm s_barrier.
//   - mi==3 A-fragment broadcasts row 48 (no OOB LDS read past xbf).
// Workspace: ~158 MB (weights + bias/mask table + bf16 O tensor).
// ---------------------------------------------------------------------------

typedef __attribute__((ext_vector_type(8))) short bfx8;  // 8 x bf16
typedef __attribute__((ext_vector_type(4))) short bfx4;  // 4 x bf16
typedef __attribute__((ext_vector_type(4))) float fx4;   // MFMA accumulator

typedef const __attribute__((address_space(1))) void* gptr_t;
typedef __attribute__((address_space(3))) void* lptr_t;

__device__ __forceinline__ short f2bf(float f) {
  union { float f; unsigned u; } v;
  v.f = f;
  unsigned r = v.u + 0x7fffu + ((v.u >> 16) & 1u);  // round-to-nearest-even
  return (short)(r >> 16);
}

// lgkm-only barrier: orders LDS writes->reads across waves WITHOUT draining
// vmcnt, so in-flight global loads (W prefetch) survive the barrier.
// Producer side needs lgkmcnt(0) BEFORE s_barrier (ds_write completion is
// what makes data visible; s_barrier alone only syncs execution).
#define LGKM_BARRIER()                                 \
  do {                                                 \
    asm volatile("s_waitcnt lgkmcnt(0)" ::: "memory"); \
    __builtin_amdgcn_s_barrier();                      \
    asm volatile("" ::: "memory");                     \
  } while (0)

// ------------------------------ prep kernels -------------------------------

// wt[n][k] = bf16(w[k][n]); w is K x N row-major.
__global__ __launch_bounds__(256) void convT_kernel(const float* __restrict__ w,
                                                    short* __restrict__ wt, int N, int K) {
  int i = blockIdx.x * 256 + threadIdx.x;
  if (i < N * K) {
    int n = i / K, k = i - n * K;
    wt[i] = f2bf(w[(size_t)k * N + n]);
  }
}

// bm[(w*6+h)*2401 + rc] = bias_table[rel_index[rc]*6 + h] + mask[w*2401 + rc]
__global__ __launch_bounds__(256) void bm_kernel(const float* __restrict__ mask,
                                                 const float* __restrict__ bias_table,
                                                 const int* __restrict__ rel_index,
                                                 float* __restrict__ bm) {
  int i = blockIdx.x * 256 + threadIdx.x;
  if (i < 64 * 6 * 2401) {
    int rc = i % 2401;
    int wh = i / 2401;
    int h = wh % 6, w = wh / 6;
    bm[i] = bias_table[rel_index[rc] * 6 + h] + mask[w * 2401 + rc];
  }
}

// ------------------------------ fused kernel -------------------------------
// One block (4 waves) per window.
// GEMM phase (n-split): wave w owns cols w*16..+15 of each of Q,K,V.
//   qacc[part][mi] over all 4 M-tiles; A-frags from swizzled x-LDS;
//   B-frags = wfrag[part][kt] registers.
// Attn phase (M-split): wave w owns rows w*16..+15 (swizzled LDS throughout).
// LDS: xbf 37,632 + (Qs,Ks,Vt,Pb) 4*8,192 = 70,400 B -> 2 blocks/CU.

__global__ __launch_bounds__(256, 2) void fused_attn_kernel(
    const float* __restrict__ x,        // [4096*49][384] fp32
    const short* __restrict__ wqkv_t,   // [1152][384] bf16 (n-major)
    const float* __restrict__ qkv_b,    // [1152]
    const float* __restrict__ bm,       // [64][6][49][49]
    short* __restrict__ O) {            // [4096*49][384] bf16
  __shared__ __align__(16) short xbf[49 * 384];  // swizzled bf16 x
  __shared__ __align__(16) short Qs[64 * 64];
  __shared__ __align__(16) short Ks[64 * 64];
  __shared__ __align__(16) short Vt[64 * 64];    // transposed: Vt[e][s]
  __shared__ __align__(16) short Pb[64 * 64];

  const int tid = threadIdx.x;
  const int lane = tid & 63, wid = tid >> 6;
  const int l15 = lane & 15, q4 = lane >> 4;
  const int b = blockIdx.x, w = b & 63;
  const float* xw = x + (size_t)b * 49 * 384;
  const float* bmp_base = bm + (size_t)(w * 6) * 2401;

  const fx4 zero = {0.f, 0.f, 0.f, 0.f};
  const bfx8 zbf = {0, 0, 0, 0, 0, 0, 0, 0};
  const int arow = wid * 16 + l15;     // attn A-row this lane reads
  const int crow = wid * 16 + q4 * 4;  // attn C-fragment base row
  const int kswz = (l15 & 7) << 3;     // col-XOR for any row with row&7==l15&7
  const int cpart = wid * 16 + l15;    // GEMM: this lane's column within part

  // ---- W fragments for head 0: wfrag[part][kt], 144 VGPR -----------------
  // Lane (l15,q4) loads wqkv_t[n = part*384 + h*64 + wid*16 + l15][kt*32+q4*8]
  // which IS the MFMA B-fragment layout. Lands under the x-stage below.
  bfx8 wfrag[3][12];
  {
    const short* wb = wqkv_t + (size_t)(wid * 16 + l15) * 384 + q4 * 8;
#pragma unroll
    for (int p = 0; p < 3; ++p)
#pragma unroll
      for (int kt = 0; kt < 12; ++kt)
        wfrag[p][kt] = *(const bfx8*)(wb + (size_t)p * 147456 + kt * 32);
  }

  // ---- stage x -> bf16 LDS (rows 0..48), XOR-swizzled ---------------------
  for (int i = tid; i < 49 * 48; i += 256) {
    const int r = i / 48, c8 = (i - r * 48) * 8;
    const float4* ap = (const float4*)(xw + (size_t)r * 384 + c8);
    const float4 a0 = ap[0], a1 = ap[1];
    bfx8 v;
    v[0] = f2bf(a0.x); v[1] = f2bf(a0.y); v[2] = f2bf(a0.z); v[3] = f2bf(a0.w);
    v[4] = f2bf(a1.x); v[5] = f2bf(a1.y); v[6] = f2bf(a1.z); v[7] = f2bf(a1.w);
    *(bfx8*)&xbf[r * 384 + (c8 ^ ((r & 7) << 3))] = v;
  }
  LGKM_BARRIER();

#pragma unroll 1
  for (int h = 0; h < 6; ++h) {
    // ---------------- QKV GEMM for head h (no barriers, no staging) --------
    fx4 qacc[3][4];
#pragma unroll
    for (int p = 0; p < 3; ++p)
#pragma unroll
      for (int mi = 0; mi < 4; ++mi) qacc[p][mi] = zero;

#pragma unroll
    for (int kt = 0; kt < 12; ++kt) {
      bfx8 af[4];
#pragma unroll
      for (int mi = 0; mi < 3; ++mi)
        af[mi] = *(const bfx8*)&xbf[(mi * 16 + l15) * 384 + ((kt * 32 + q4 * 8) ^ kswz)];
      {
        // M-tile 3: only row 48 is real; row 48 swizzle is identity (48&7==0).
        const bfx8 v48 = *(const bfx8*)&xbf[48 * 384 + kt * 32 + q4 * 8];
        af[3] = (l15 == 0) ? v48 : zbf;
      }
#pragma unroll
      for (int p = 0; p < 3; ++p)
#pragma unroll
        for (int mi = 0; mi < 4; ++mi)
          qacc[p][mi] =
              __builtin_amdgcn_mfma_f32_16x16x32_bf16(af[mi], wfrag[p][kt], qacc[p][mi], 0, 0, 0);
    }

    // bias+mask loads issued BEFORE the W prefetch so their waitcnt does not
    // drain the W loads (FIFO vmcnt).
    const float* bmp = bmp_base + (size_t)h * 2401;
    float bmv[4][4];
#pragma unroll
    for (int nt = 0; nt < 4; ++nt)
#pragma unroll
      for (int rr = 0; rr < 4; ++rr) {
        const int r = crow + rr, c = nt * 16 + l15;
        bmv[nt][rr] = (r < 49 && c < 49) ? bmp[r * 49 + c] : -1e30f;
      }

    // prefetch W(h+1) into the now-dead wfrag regs; lands under epi+attn.
    if (h < 5) {
      const short* wb = wqkv_t + (size_t)((h + 1) * 64 + wid * 16 + l15) * 384 + q4 * 8;
#pragma unroll
      for (int p = 0; p < 3; ++p)
#pragma unroll
        for (int kt = 0; kt < 12; ++kt)
          wfrag[p][kt] = *(const bfx8*)(wb + (size_t)p * 147456 + kt * 32);
    }

    // ---------------- epilogue: qacc -> Qs/Ks/Vt (swizzled) ----------------
    const float bq = qkv_b[h * 64 + cpart];
    const float bk = qkv_b[384 + h * 64 + cpart];
    const float bv = qkv_b[768 + h * 64 + cpart];
#pragma unroll
    for (int mi = 0; mi < 4; ++mi) {
#pragma unroll
      for (int rr = 0; rr < 4; ++rr) {
        const int r = mi * 16 + q4 * 4 + rr;
        const int cs = cpart ^ ((r & 7) << 3);
        Qs[r * 64 + cs] = f2bf((qacc[0][mi][rr] + bq) * 0.125f);
        Ks[r * 64 + cs] = f2bf(qacc[1][mi][rr] + bk);
      }
      // V transposed: row e=cpart, 4 consecutive s -> one b64 write
      bfx4 vv;
#pragma unroll
      for (int rr = 0; rr < 4; ++rr) vv[rr] = f2bf(qacc[2][mi][rr] + bv);
      const int s0 = mi * 16 + q4 * 4;
      *(bfx4*)&Vt[cpart * 64 + (s0 ^ kswz)] = vv;
    }
    LGKM_BARRIER();  // Qs/Ks/Vt visible; W prefetch still in flight

    // ---------------- S = Q @ K^T (M-split: rows wid*16..) -----------------
    fx4 sacc[4];
#pragma unroll
    for (int i = 0; i < 4; ++i) sacc[i] = zero;
#pragma unroll
    for (int ks = 0; ks < 2; ++ks) {
      const bfx8 aq = *(const bfx8*)&Qs[arow * 64 + ((ks * 32 + q4 * 8) ^ kswz)];
#pragma unroll
      for (int nt = 0; nt < 4; ++nt) {
        const bfx8 bkf = *(const bfx8*)&Ks[(nt * 16 + l15) * 64 + ((ks * 32 + q4 * 8) ^ kswz)];
        sacc[nt] = __builtin_amdgcn_mfma_f32_16x16x32_bf16(aq, bkf, sacc[nt], 0, 0, 0);
      }
    }

    // ---------------- in-register softmax ----------------------------------
    // Row q=crow+rr lives across the 16 lanes sharing q4 (cols nt*16+l15);
    // shfl_xor 1/2/4/8 reduces within that group. Pad cols get -1e30 ->
    // exp -> exact 0; pad rows are finite garbage discarded at the O-store.
    float p[4][4], mx[4], sm[4];
#pragma unroll
    for (int rr = 0; rr < 4; ++rr) mx[rr] = -1e30f;
#pragma unroll
    for (int nt = 0; nt < 4; ++nt)
#pragma unroll
      for (int rr = 0; rr < 4; ++rr) {
        p[nt][rr] = sacc[nt][rr] + bmv[nt][rr];
        mx[rr] = fmaxf(mx[rr], p[nt][rr]);
      }
#pragma unroll
    for (int rr = 0; rr < 4; ++rr) {
      mx[rr] = fmaxf(mx[rr], __shfl_xor(mx[rr], 1));
      mx[rr] = fmaxf(mx[rr], __shfl_xor(mx[rr], 2));
      mx[rr] = fmaxf(mx[rr], __shfl_xor(mx[rr], 4));
      mx[rr] = fmaxf(mx[rr], __shfl_xor(mx[rr], 8));
      sm[rr] = 0.f;
    }
#pragma unroll
    for (int nt = 0; nt < 4; ++nt)
#pragma unroll
      for (int rr = 0; rr < 4; ++rr) {
        const float e = __expf(p[nt][rr] - mx[rr]);
        p[nt][rr] = e;
        sm[rr] += e;
      }
#pragma unroll
    for (int rr = 0; rr < 4; ++rr) {
      sm[rr] += __shfl_xor(sm[rr], 1);
      sm[rr] += __shfl_xor(sm[rr], 2);
      sm[rr] += __shfl_xor(sm[rr], 4);
      sm[rr] += __shfl_xor(sm[rr], 8);
      sm[rr] = 1.f / sm[rr];
    }
    // P -> Pb (wave-local rows; PV reads only this wave's strip -> no barrier)
#pragma unroll
    for (int nt = 0; nt < 4; ++nt)
#pragma unroll
      for (int rr = 0; rr < 4; ++rr) {
        const int r = crow + rr;
        Pb[r * 64 + ((nt * 16 + l15) ^ ((r & 7) << 3))] = f2bf(p[nt][rr] * sm[rr]);
      }

    // ---------------- O_h = P @ V -> global bf16 ---------------------------
    fx4 oacc[4];
#pragma unroll
    for (int i = 0; i < 4; ++i) oacc[i] = zero;
#pragma unroll
    for (int ks = 0; ks < 2; ++ks) {
      const bfx8 ap = *(const bfx8*)&Pb[arow * 64 + ((ks * 32 + q4 * 8) ^ kswz)];
#pragma unroll
      for (int nt = 0; nt < 4; ++nt) {
        const bfx8 bvf = *(const bfx8*)&Vt[(nt * 16 + l15) * 64 + ((ks * 32 + q4 * 8) ^ kswz)];
        oacc[nt] = __builtin_amdgcn_mfma_f32_16x16x32_bf16(ap, bvf, oacc[nt], 0, 0, 0);
      }
    }
#pragma unroll
    for (int nt = 0; nt < 4; ++nt)
#pragma unroll
      for (int rr = 0; rr < 4; ++rr) {
        const int r = crow + rr;
        if (r < 49)
          O[((size_t)b * 49 + r) * 384 + h * 64 + nt * 16 + l15] = f2bf(oacc[nt][rr]);
      }
    LGKM_BARRIER();  // attn LDS reads done before next head's epilogue writes
  }  // heads
}

// ------------------------------ proj kernel --------------------------------
// out = O @ proj_w + proj_b.  M=200704, N=384, K=384. 128x128 tile, 4 waves.

__global__ __launch_bounds__(256) void proj_kernel(
    const short* __restrict__ O,        // [200704][384] bf16
    const short* __restrict__ wproj_t,  // [384][384] bf16 (n-major)
    const float* __restrict__ proj_b,   // [384]
    float* __restrict__ out) {          // [200704][384] fp32
  __shared__ __align__(16) short As[128 * 32];
  __shared__ __align__(16) short Bs[128 * 32];

  const int tid = threadIdx.x;
  const int lane = tid & 63, wid = tid >> 6;
  const int l15 = lane & 15, q4 = lane >> 4;
  const int tn = blockIdx.x % 3, tm = blockIdx.x / 3;
  const int wr = wid >> 1, wc = wid & 1;  // 2x2 wave grid

  const short* Abase = O + (size_t)tm * 128 * 384;
  const short* Bbase = wproj_t + (size_t)tn * 128 * 384;

  fx4 acc[4][4];
#pragma unroll
  for (int i = 0; i < 4; ++i)
#pragma unroll
    for (int j = 0; j < 4; ++j) acc[i][j] = (fx4){0.f, 0.f, 0.f, 0.f};

  for (int kt = 0; kt < 12; ++kt) {
#pragma unroll
    for (int g = 0; g < 2; ++g) {
      const int off = g * 4096 + tid * 16;
      const int row = off >> 6;
      const int ce = (off & 63) >> 1;
      __builtin_amdgcn_global_load_lds(
          (gptr_t)(Abase + (size_t)row * 384 + kt * 32 + ce),
          (lptr_t)((char*)As + off), 16, 0, 0);
      __builtin_amdgcn_global_load_lds(
          (gptr_t)(Bbase + (size_t)row * 384 + kt * 32 + ce),
          (lptr_t)((char*)Bs + off), 16, 0, 0);
    }
    __syncthreads();
    bfx8 a[4], bf[4];
#pragma unroll
    for (int mi = 0; mi < 4; ++mi)
      a[mi] = *(const bfx8*)&As[(wr * 64 + mi * 16 + l15) * 32 + q4 * 8];
#pragma unroll
    for (int ni = 0; ni < 4; ++ni)
      bf[ni] = *(const bfx8*)&Bs[(wc * 64 + ni * 16 + l15) * 32 + q4 * 8];
#pragma unroll
    for (int mi = 0; mi < 4; ++mi)
#pragma unroll
      for (int ni = 0; ni < 4; ++ni)
        acc[mi][ni] = __builtin_amdgcn_mfma_f32_16x16x32_bf16(a[mi], bf[ni], acc[mi][ni], 0, 0, 0);
    __syncthreads();
  }

#pragma unroll
  for (int ni = 0; ni < 4; ++ni) {
    const int gn = tn * 128 + wc * 64 + ni * 16 + l15;
    const float bias = proj_b[gn];
#pragma unroll
    for (int mi = 0; mi < 4; ++mi) {
      const size_t gm = (size_t)tm * 128 + wr * 64 + mi * 16 + q4 * 4;
#pragma unroll
      for (int rr = 0; rr < 4; ++rr)
        out[(gm + rr) * 384 + gn] = acc[mi][ni][rr] + bias;
    }
  }
}

// ------------------------------- launcher ----------------------------------

extern "C" void kernel_launch(void* const* d_in, const int* in_sizes, int n_in,
                              void* d_out, int out_size, void* d_ws, size_t ws_size,
                              hipStream_t stream) {
  const float* x       = (const float*)d_in[0];
  const float* mask    = (const float*)d_in[1];
  const float* qkv_w   = (const float*)d_in[2];
  const float* qkv_b   = (const float*)d_in[3];
  const float* proj_w  = (const float*)d_in[4];
  const float* proj_b  = (const float*)d_in[5];
  const float* bias_t  = (const float*)d_in[6];
  const int*   rel_idx = (const int*)d_in[7];
  float* out = (float*)d_out;

  char* ws = (char*)d_ws;
  short* wqkv_t  = (short*)(ws);                       // 1152*384*2 =   884,736 B
  short* wproj_t = (short*)(ws + 884736);              //  384*384*2 =   294,912 B
  float* bmw     = (float*)(ws + 884736 + 294912);     // 64*6*49*49*4 = 3,687,936 B
  short* O_ws    = (short*)(ws + 884736 + 294912 + 3687936);
  // O_ws: 4096*49*384*2 = 154,140,672 B ; total workspace ~158 MB

  convT_kernel<<<1728, 256, 0, stream>>>(qkv_w, wqkv_t, 1152, 384);
  convT_kernel<<<576, 256, 0, stream>>>(proj_w, wproj_t, 384, 384);
  bm_kernel<<<3602, 256, 0, stream>>>(mask, bias_t, rel_idx, bmw);

  fused_attn_kernel<<<4096, 256, 0, stream>>>(x, wqkv_t, qkv_b, bmw, O_ws);
  proj_kernel<<<4704, 256, 0, stream>>>(O_ws, wproj_t, proj_b, out);
}

// Round 4
// 1083.253 us; speedup vs baseline: 1.9030x; 1.9030x over previous
//
#include <hip/hip_runtime.h>

// ---------------------------------------------------------------------------
// WindowAttention on MI355X (gfx950) — v4: bounded-residency streamed weights.
// B_=4096 windows, S=49 (7x7), D=384, H=6 heads, hd=64, Wn=64 masks.
//
// v3 lesson (rocprof): full W-head residency (144 VGPR) spilled to scratch
// (VGPR_Count=128, WRITE_SIZE +332MB, FETCH +830MB, 2.4x slower). v4 keeps
// the barrier-free k-loop but holds only HALF a head's W per wave:
//   - wf[3][6] (72 VGPR), loop-carried through an unroll-1 kh-loop; refilled
//     after each half's MFMAs (sched_barrier(0) pins loads after MFMAs).
//     kh=1's refill fetches the NEXT head's first half -> overlaps attention.
//   - bmv + qkv-bias loads issued before any refill (FIFO vmcnt: their waits
//     don't drain the younger W loads).
//   - Pb aliased onto Qs (QPb): Qs rows [16w,16w+16) are wave-w-private in
//     the read phase, and Pb writes hit exactly those rows -> safe, -8KB LDS.
//   - pre-epilogue barrier (not end-of-head): GEMM phase barrier-free.
// LDS: xbf 37,632 + QPb/Ks/Vt 3*8,192 = 62,208 B -> 2 blocks/CU.
// Workspace: ~158 MB (weights + bias/mask table + bf16 O tensor).
// ---------------------------------------------------------------------------

typedef __attribute__((ext_vector_type(8))) short bfx8;  // 8 x bf16
typedef __attribute__((ext_vector_type(4))) short bfx4;  // 4 x bf16
typedef __attribute__((ext_vector_type(4))) float fx4;   // MFMA accumulator

typedef const __attribute__((address_space(1))) void* gptr_t;
typedef __attribute__((address_space(3))) void* lptr_t;

__device__ __forceinline__ short f2bf(float f) {
  union { float f; unsigned u; } v;
  v.f = f;
  unsigned r = v.u + 0x7fffu + ((v.u >> 16) & 1u);  // round-to-nearest-even
  return (short)(r >> 16);
}

// lgkm-only barrier: orders LDS writes->reads across waves WITHOUT draining
// vmcnt, so in-flight global loads (W refill) survive the barrier.
#define LGKM_BARRIER()                                 \
  do {                                                 \
    asm volatile("s_waitcnt lgkmcnt(0)" ::: "memory"); \
    __builtin_amdgcn_s_barrier();                      \
    asm volatile("" ::: "memory");                     \
  } while (0)

// ------------------------------ prep kernels -------------------------------

// wt[n][k] = bf16(w[k][n]); w is K x N row-major.
__global__ __launch_bounds__(256) void convT_kernel(const float* __restrict__ w,
                                                    short* __restrict__ wt, int N, int K) {
  int i = blockIdx.x * 256 + threadIdx.x;
  if (i < N * K) {
    int n = i / K, k = i - n * K;
    wt[i] = f2bf(w[(size_t)k * N + n]);
  }
}

// bm[(w*6+h)*2401 + rc] = bias_table[rel_index[rc]*6 + h] + mask[w*2401 + rc]
__global__ __launch_bounds__(256) void bm_kernel(const float* __restrict__ mask,
                                                 const float* __restrict__ bias_table,
                                                 const int* __restrict__ rel_index,
                                                 float* __restrict__ bm) {
  int i = blockIdx.x * 256 + threadIdx.x;
  if (i < 64 * 6 * 2401) {
    int rc = i % 2401;
    int wh = i / 2401;
    int h = wh % 6, w = wh / 6;
    bm[i] = bias_table[rel_index[rc] * 6 + h] + mask[w * 2401 + rc];
  }
}

// ------------------------------ fused kernel -------------------------------
// One block (4 waves) per window.
// GEMM phase (n-split): wave w owns cols w*16..+15 of each of Q,K,V; A-frags
// from swizzled x-LDS; B-frags = wf registers (one k-half at a time).
// Attn phase (M-split): wave w owns rows w*16..+15 (swizzled LDS).

__global__ __launch_bounds__(256, 2) void fused_attn_kernel(
    const float* __restrict__ x,        // [4096*49][384] fp32
    const short* __restrict__ wqkv_t,   // [1152][384] bf16 (n-major)
    const float* __restrict__ qkv_b,    // [1152]
    const float* __restrict__ bm,       // [64][6][49][49]
    short* __restrict__ O) {            // [4096*49][384] bf16
  __shared__ __align__(16) short xbf[49 * 384];  // swizzled bf16 x
  __shared__ __align__(16) short QPb[64 * 64];   // Q (GEMM out), then P
  __shared__ __align__(16) short Ks[64 * 64];
  __shared__ __align__(16) short Vt[64 * 64];    // transposed: Vt[e][s]

  const int tid = threadIdx.x;
  const int lane = tid & 63, wid = tid >> 6;
  const int l15 = lane & 15, q4 = lane >> 4;
  const int b = blockIdx.x, w = b & 63;
  const float* xw = x + (size_t)b * 49 * 384;
  const float* bmp_base = bm + (size_t)(w * 6) * 2401;

  const fx4 zero = {0.f, 0.f, 0.f, 0.f};
  const bfx8 zbf = {0, 0, 0, 0, 0, 0, 0, 0};
  const int arow = wid * 16 + l15;     // attn A-row this lane reads
  const int crow = wid * 16 + q4 * 4;  // attn C-fragment base row
  const int kswz = (l15 & 7) << 3;     // col-XOR for rows with row&7==l15&7
  const int cpart = wid * 16 + l15;    // GEMM: this lane's column within part

  // ---- W fragments, one k-half: wf[part][ktl], 72 VGPR, loop-carried ------
  // Lane (l15,q4) holds wqkv_t[n = p*384 + h*64 + wid*16+l15][k0 + ktl*32+q4*8]
  // == the MFMA B-fragment layout. Initial fill: h=0, half 0 (overlaps x-stage).
  bfx8 wf[3][6];
  {
    const short* wb = wqkv_t + (size_t)(wid * 16 + l15) * 384 + q4 * 8;
#pragma unroll
    for (int p = 0; p < 3; ++p)
#pragma unroll
      for (int ktl = 0; ktl < 6; ++ktl)
        wf[p][ktl] = *(const bfx8*)(wb + (size_t)p * 147456 + ktl * 32);
  }

  // ---- stage x -> bf16 LDS (rows 0..48), XOR-swizzled ---------------------
  for (int i = tid; i < 49 * 48; i += 256) {
    const int r = i / 48, c8 = (i - r * 48) * 8;
    const float4* ap = (const float4*)(xw + (size_t)r * 384 + c8);
    const float4 a0 = ap[0], a1 = ap[1];
    bfx8 v;
    v[0] = f2bf(a0.x); v[1] = f2bf(a0.y); v[2] = f2bf(a0.z); v[3] = f2bf(a0.w);
    v[4] = f2bf(a1.x); v[5] = f2bf(a1.y); v[6] = f2bf(a1.z); v[7] = f2bf(a1.w);
    *(bfx8*)&xbf[r * 384 + (c8 ^ ((r & 7) << 3))] = v;
  }
  LGKM_BARRIER();

#pragma unroll 1
  for (int h = 0; h < 6; ++h) {
    // bias+mask loads FIRST: older than any W refill in the vmcnt FIFO, so
    // waiting on them at the epilogue/softmax leaves W loads in flight.
    const float* bmp = bmp_base + (size_t)h * 2401;
    float bmv[4][4];
#pragma unroll
    for (int nt = 0; nt < 4; ++nt)
#pragma unroll
      for (int rr = 0; rr < 4; ++rr) {
        const int r = crow + rr, c = nt * 16 + l15;
        bmv[nt][rr] = (r < 49 && c < 49) ? bmp[r * 49 + c] : -1e30f;
      }
    const float bq = qkv_b[h * 64 + cpart];
    const float bk = qkv_b[384 + h * 64 + cpart];
    const float bv = qkv_b[768 + h * 64 + cpart];

    // ---------------- QKV GEMM for head h (no barriers, no staging) --------
    fx4 qacc[3][4];
#pragma unroll
    for (int p = 0; p < 3; ++p)
#pragma unroll
      for (int mi = 0; mi < 4; ++mi) qacc[p][mi] = zero;

#pragma unroll 1
    for (int kh = 0; kh < 2; ++kh) {
      const int kb = kh * 192;
#pragma unroll
      for (int ktl = 0; ktl < 6; ++ktl) {
        const int kc = kb + ktl * 32 + q4 * 8;
        bfx8 af[4];
#pragma unroll
        for (int mi = 0; mi < 3; ++mi)
          af[mi] = *(const bfx8*)&xbf[(mi * 16 + l15) * 384 + (kc ^ kswz)];
        {
          // M-tile 3: only row 48 real; row 48 swizzle is identity (48&7==0).
          const bfx8 v48 = *(const bfx8*)&xbf[48 * 384 + kc];
          af[3] = (l15 == 0) ? v48 : zbf;
        }
#pragma unroll
        for (int p = 0; p < 3; ++p)
#pragma unroll
          for (int mi = 0; mi < 4; ++mi)
            qacc[p][mi] =
                __builtin_amdgcn_mfma_f32_16x16x32_bf16(af[mi], wf[p][ktl], qacc[p][mi], 0, 0, 0);
      }
      // Pin the refill AFTER the MFMAs that consume the old wf (prevents the
      // scheduler from doubling W residency -> the v3 spill).
      __builtin_amdgcn_sched_barrier(0);
      // refill wf: kh=0 -> this head's half 1; kh=1 -> next head's half 0
      // (lands under epilogue + attention).
      const int nh = (kh == 0) ? h : h + 1;
      const int nk = (kh == 0) ? 192 : 0;
      if (nh < 6) {
        const short* wb = wqkv_t + (size_t)(nh * 64 + wid * 16 + l15) * 384 + nk + q4 * 8;
#pragma unroll
        for (int p = 0; p < 3; ++p)
#pragma unroll
          for (int ktl = 0; ktl < 6; ++ktl)
            wf[p][ktl] = *(const bfx8*)(wb + (size_t)p * 147456 + ktl * 32);
      }
    }

    // ---------------- epilogue: qacc -> QPb(Q)/Ks/Vt (swizzled) ------------
    LGKM_BARRIER();  // all waves done with prev head's attn LDS reads
#pragma unroll
    for (int mi = 0; mi < 4; ++mi) {
#pragma unroll
      for (int rr = 0; rr < 4; ++rr) {
        const int r = mi * 16 + q4 * 4 + rr;
        const int cs = cpart ^ ((r & 7) << 3);
        QPb[r * 64 + cs] = f2bf((qacc[0][mi][rr] + bq) * 0.125f);
        Ks[r * 64 + cs] = f2bf(qacc[1][mi][rr] + bk);
      }
      // V transposed: row e=cpart, 4 consecutive s -> one b64 write
      bfx4 vv;
#pragma unroll
      for (int rr = 0; rr < 4; ++rr) vv[rr] = f2bf(qacc[2][mi][rr] + bv);
      const int s0 = mi * 16 + q4 * 4;
      *(bfx4*)&Vt[cpart * 64 + (s0 ^ kswz)] = vv;
    }
    LGKM_BARRIER();  // Q/K/V visible; W refill still in flight

    // ---------------- S = Q @ K^T (M-split: rows wid*16..) -----------------
    fx4 sacc[4];
#pragma unroll
    for (int i = 0; i < 4; ++i) sacc[i] = zero;
#pragma unroll
    for (int ks = 0; ks < 2; ++ks) {
      const bfx8 aq = *(const bfx8*)&QPb[arow * 64 + ((ks * 32 + q4 * 8) ^ kswz)];
#pragma unroll
      for (int nt = 0; nt < 4; ++nt) {
        const bfx8 bkf = *(const bfx8*)&Ks[(nt * 16 + l15) * 64 + ((ks * 32 + q4 * 8) ^ kswz)];
        sacc[nt] = __builtin_amdgcn_mfma_f32_16x16x32_bf16(aq, bkf, sacc[nt], 0, 0, 0);
      }
    }

    // ---------------- in-register softmax ----------------------------------
    // Row q=crow+rr lives across the 16 lanes sharing q4 (cols nt*16+l15);
    // shfl_xor 1/2/4/8 reduces within the group. Pad cols get -1e30 -> exp
    // -> exact 0; pad rows are finite garbage discarded at the O-store.
    float p[4][4], mx[4], sm[4];
#pragma unroll
    for (int rr = 0; rr < 4; ++rr) mx[rr] = -1e30f;
#pragma unroll
    for (int nt = 0; nt < 4; ++nt)
#pragma unroll
      for (int rr = 0; rr < 4; ++rr) {
        p[nt][rr] = sacc[nt][rr] + bmv[nt][rr];
        mx[rr] = fmaxf(mx[rr], p[nt][rr]);
      }
#pragma unroll
    for (int rr = 0; rr < 4; ++rr) {
      mx[rr] = fmaxf(mx[rr], __shfl_xor(mx[rr], 1));
      mx[rr] = fmaxf(mx[rr], __shfl_xor(mx[rr], 2));
      mx[rr] = fmaxf(mx[rr], __shfl_xor(mx[rr], 4));
      mx[rr] = fmaxf(mx[rr], __shfl_xor(mx[rr], 8));
      sm[rr] = 0.f;
    }
#pragma unroll
    for (int nt = 0; nt < 4; ++nt)
#pragma unroll
      for (int rr = 0; rr < 4; ++rr) {
        const float e = __expf(p[nt][rr] - mx[rr]);
        p[nt][rr] = e;
        sm[rr] += e;
      }
#pragma unroll
    for (int rr = 0; rr < 4; ++rr) {
      sm[rr] += __shfl_xor(sm[rr], 1);
      sm[rr] += __shfl_xor(sm[rr], 2);
      sm[rr] += __shfl_xor(sm[rr], 4);
      sm[rr] += __shfl_xor(sm[rr], 8);
      sm[rr] = 1.f / sm[rr];
    }
    // P -> QPb rows crow..+3: exactly the rows only THIS wave read as the
    // QK^T A-operand (same array -> compiler sees the dependency; no barrier).
#pragma unroll
    for (int nt = 0; nt < 4; ++nt)
#pragma unroll
      for (int rr = 0; rr < 4; ++rr) {
        const int r = crow + rr;
        QPb[r * 64 + ((nt * 16 + l15) ^ ((r & 7) << 3))] = f2bf(p[nt][rr] * sm[rr]);
      }

    // ---------------- O_h = P @ V -> global bf16 ---------------------------
    fx4 oacc[4];
#pragma unroll
    for (int i = 0; i < 4; ++i) oacc[i] = zero;
#pragma unroll
    for (int ks = 0; ks < 2; ++ks) {
      const bfx8 ap = *(const bfx8*)&QPb[arow * 64 + ((ks * 32 + q4 * 8) ^ kswz)];
#pragma unroll
      for (int nt = 0; nt < 4; ++nt) {
        const bfx8 bvf = *(const bfx8*)&Vt[(nt * 16 + l15) * 64 + ((ks * 32 + q4 * 8) ^ kswz)];
        oacc[nt] = __builtin_amdgcn_mfma_f32_16x16x32_bf16(ap, bvf, oacc[nt], 0, 0, 0);
      }
    }
#pragma unroll
    for (int nt = 0; nt < 4; ++nt)
#pragma unroll
      for (int rr = 0; rr < 4; ++rr) {
        const int r = crow + rr;
        if (r < 49)
          O[((size_t)b * 49 + r) * 384 + h * 64 + nt * 16 + l15] = f2bf(oacc[nt][rr]);
      }
  }  // heads
}

// ------------------------------ proj kernel --------------------------------
// out = O @ proj_w + proj_b.  M=200704, N=384, K=384. 128x128 tile, 4 waves.

__global__ __launch_bounds__(256) void proj_kernel(
    const short* __restrict__ O,        // [200704][384] bf16
    const short* __restrict__ wproj_t,  // [384][384] bf16 (n-major)
    const float* __restrict__ proj_b,   // [384]
    float* __restrict__ out) {          // [200704][384] fp32
  __shared__ __align__(16) short As[128 * 32];
  __shared__ __align__(16) short Bs[128 * 32];

  const int tid = threadIdx.x;
  const int lane = tid & 63, wid = tid >> 6;
  const int l15 = lane & 15, q4 = lane >> 4;
  const int tn = blockIdx.x % 3, tm = blockIdx.x / 3;
  const int wr = wid >> 1, wc = wid & 1;  // 2x2 wave grid

  const short* Abase = O + (size_t)tm * 128 * 384;
  const short* Bbase = wproj_t + (size_t)tn * 128 * 384;

  fx4 acc[4][4];
#pragma unroll
  for (int i = 0; i < 4; ++i)
#pragma unroll
    for (int j = 0; j < 4; ++j) acc[i][j] = (fx4){0.f, 0.f, 0.f, 0.f};

  for (int kt = 0; kt < 12; ++kt) {
#pragma unroll
    for (int g = 0; g < 2; ++g) {
      const int off = g * 4096 + tid * 16;
      const int row = off >> 6;
      const int ce = (off & 63) >> 1;
      __builtin_amdgcn_global_load_lds(
          (gptr_t)(Abase + (size_t)row * 384 + kt * 32 + ce),
          (lptr_t)((char*)As + off), 16, 0, 0);
      __builtin_amdgcn_global_load_lds(
          (gptr_t)(Bbase + (size_t)row * 384 + kt * 32 + ce),
          (lptr_t)((char*)Bs + off), 16, 0, 0);
    }
    __syncthreads();
    bfx8 a[4], bf[4];
#pragma unroll
    for (int mi = 0; mi < 4; ++mi)
      a[mi] = *(const bfx8*)&As[(wr * 64 + mi * 16 + l15) * 32 + q4 * 8];
#pragma unroll
    for (int ni = 0; ni < 4; ++ni)
      bf[ni] = *(const bfx8*)&Bs[(wc * 64 + ni * 16 + l15) * 32 + q4 * 8];
#pragma unroll
    for (int mi = 0; mi < 4; ++mi)
#pragma unroll
      for (int ni = 0; ni < 4; ++ni)
        acc[mi][ni] = __builtin_amdgcn_mfma_f32_16x16x32_bf16(a[mi], bf[ni], acc[mi][ni], 0, 0, 0);
    __syncthreads();
  }

#pragma unroll
  for (int ni = 0; ni < 4; ++ni) {
    const int gn = tn * 128 + wc * 64 + ni * 16 + l15;
    const float bias = proj_b[gn];
#pragma unroll
    for (int mi = 0; mi < 4; ++mi) {
      const size_t gm = (size_t)tm * 128 + wr * 64 + mi * 16 + q4 * 4;
#pragma unroll
      for (int rr = 0; rr < 4; ++rr)
        out[(gm + rr) * 384 + gn] = acc[mi][ni][rr] + bias;
    }
  }
}

// ------------------------------- launcher ----------------------------------

extern "C" void kernel_launch(void* const* d_in, const int* in_sizes, int n_in,
                              void* d_out, int out_size, void* d_ws, size_t ws_size,
                              hipStream_t stream) {
  const float* x       = (const float*)d_in[0];
  const float* mask    = (const float*)d_in[1];
  const float* qkv_w   = (const float*)d_in[2];
  const float* qkv_b   = (const float*)d_in[3];
  const float* proj_w  = (const float*)d_in[4];
  const float* proj_b  = (const float*)d_in[5];
  const float* bias_t  = (const float*)d_in[6];
  const int*   rel_idx = (const int*)d_in[7];
  float* out = (float*)d_out;

  char* ws = (char*)d_ws;
  short* wqkv_t  = (short*)(ws);                       // 1152*384*2 =   884,736 B
  short* wproj_t = (short*)(ws + 884736);              //  384*384*2 =   294,912 B
  float* bmw     = (float*)(ws + 884736 + 294912);     // 64*6*49*49*4 = 3,687,936 B
  short* O_ws    = (short*)(ws + 884736 + 294912 + 3687936);
  // O_ws: 4096*49*384*2 = 154,140,672 B ; total workspace ~158 MB

  convT_kernel<<<1728, 256, 0, stream>>>(qkv_w, wqkv_t, 1152, 384);
  convT_kernel<<<576, 256, 0, stream>>>(proj_w, wproj_t, 384, 384);
  bm_kernel<<<3602, 256, 0, stream>>>(mask, bias_t, rel_idx, bmw);

  fused_attn_kernel<<<4096, 256, 0, stream>>>(x, wqkv_t, qkv_b, bmw, O_ws);
  proj_kernel<<<4704, 256, 0, stream>>>(O_ws, wproj_t, proj_b, out);
}